// Round 1
// baseline (165.612 us; speedup 1.0000x reference)
//
#include <hip/hip_runtime.h>
#include <stdint.h>

// ModulatedConv (StyleGAN2 up-conv): B=8, Cin=Cout=512, K=3, 32x32 -> 64x64, fp32 I/O.
// Pipeline (3 kernels):
//   K1 k_prep:  blocks 0..511  = dcoef + Wm[b][tap][o][i] bf16 (37.75 MB), block per o
//               blocks 512..1023 = XT[b][hw][i] bf16 (8.39 MB) transpose
//   K2 k_gemm:  256x256-tile 8-phase schedule (T2 swizzle + T3/T4 counted vmcnt + T5
//               setprio), 72 GEMMs 512x1024x512 bf16 -> C[b*9+tap][o][hw] (75.5 MB)
//   K3 k_fir:   parity scatter + separable 4x4 FIR per (b,o), 512 thr, padded V

#define DI __device__ __forceinline__

typedef __bf16 bf16x8 __attribute__((ext_vector_type(8)));
typedef float f32x4 __attribute__((ext_vector_type(4)));

DI float bf2f(ushort u) { union { uint32_t i; float f; } v; v.i = ((uint32_t)u) << 16; return v.f; }
DI ushort f2bf(float f) {
  union { float f; uint32_t i; } v; v.f = f;
  uint32_t x = v.i;
  return (ushort)((x + 0x7FFFu + ((x >> 16) & 1u)) >> 16);  // RNE
}

#define GAIN (1.0f / 1536.0f)  // 1/sqrt(512*512*9)

// ---------------- K1: fused weight-prep (blocks 0..511) + x-transpose (512..1023) -------
__global__ __launch_bounds__(256) void k_prep(const float* __restrict__ w,
                                              const float* __restrict__ styles,
                                              const float* __restrict__ x,
                                              ushort* __restrict__ Wm,
                                              ushort* __restrict__ xt) {
  __shared__ union {
    struct { float ss[4096]; float dc[8]; float wred[4][8]; } wp;
    float tl[32][257];
  } sm;
  const int t = threadIdx.x;
  if (blockIdx.x < 512) {
    // ---- weight prep: block per o. Thread t owns i = 2t, 2t+1. ----
    const int o = blockIdx.x;
#pragma unroll
    for (int j = 0; j < 4; j++) {
      const int idx = (t + j * 256) * 4;
      *(float4*)&sm.wp.ss[idx] = *(const float4*)&styles[idx];
    }
    float wreg[18];
    const float* wp_ = w + o * 4608 + t * 18;
#pragma unroll
    for (int k = 0; k < 9; k++) {
      float2 v2 = *(const float2*)(wp_ + 2 * k);
      wreg[2 * k] = v2.x;
      wreg[2 * k + 1] = v2.y;
    }
    float q0 = 0.f, q1 = 0.f;
#pragma unroll
    for (int k = 0; k < 9; k++) {
      q0 += wreg[k] * wreg[k];
      q1 += wreg[9 + k] * wreg[9 + k];
    }
    __syncthreads();  // ss ready
    float pb[8];
#pragma unroll
    for (int b = 0; b < 8; b++) {
      float s0 = sm.wp.ss[b * 512 + 2 * t] + 1.0f;
      float s1 = sm.wp.ss[b * 512 + 2 * t + 1] + 1.0f;
      pb[b] = s0 * s0 * q0 + s1 * s1 * q1;
    }
#pragma unroll
    for (int b = 0; b < 8; b++)
#pragma unroll
      for (int off = 32; off > 0; off >>= 1) pb[b] += __shfl_down(pb[b], off, 64);
    const int wid = t >> 6, lane = t & 63;
    if (lane == 0) {
#pragma unroll
      for (int b = 0; b < 8; b++) sm.wp.wred[wid][b] = pb[b];
    }
    __syncthreads();
    if (t < 8)
      sm.wp.dc[t] = rsqrtf((sm.wp.wred[0][t] + sm.wp.wred[1][t] + sm.wp.wred[2][t] + sm.wp.wred[3][t]) *
                               (GAIN * GAIN) + 1e-8f);
    __syncthreads();
#pragma unroll
    for (int b = 0; b < 8; b++) {
      const float d = sm.wp.dc[b];
      const float s0 = GAIN * (sm.wp.ss[b * 512 + 2 * t] + 1.0f) * d;
      const float s1 = GAIN * (sm.wp.ss[b * 512 + 2 * t + 1] + 1.0f) * d;
      ushort* base = Wm + ((size_t)(b * 9) * 512 + o) * 512 + 2 * t;
#pragma unroll
      for (int tap = 0; tap < 9; tap++) {
        ushort2 val = make_ushort2(f2bf(wreg[tap] * s0), f2bf(wreg[9 + tap] * s1));
        *(ushort2*)(base + (size_t)tap * 262144) = val;
      }
    }
  } else {
    // ---- x transpose: tile 32 i x 256 hw ----
    const int idx = blockIdx.x - 512;
    const int hw0 = (idx & 3) * 256, i0 = ((idx >> 2) & 15) * 32, b = idx >> 6;
    const float* xb = x + b * (512 * 1024);
#pragma unroll
    for (int p = 0; p < 8; p++) {
      const int r = p * 4 + (t >> 6);
      const int c4 = (t & 63) * 4;
      float4 v = *(const float4*)&xb[(i0 + r) * 1024 + hw0 + c4];
      sm.tl[r][c4] = v.x; sm.tl[r][c4 + 1] = v.y; sm.tl[r][c4 + 2] = v.z; sm.tl[r][c4 + 3] = v.w;
    }
    __syncthreads();
    ushort* xtb = xt + b * (1024 * 512);
#pragma unroll
    for (int p = 0; p < 8; p++) {
      const int hw = p * 32 + (t >> 3);
      const int i4 = (t & 7) * 4;
      ushort4 v = make_ushort4(f2bf(sm.tl[i4][hw]), f2bf(sm.tl[i4 + 1][hw]),
                               f2bf(sm.tl[i4 + 2][hw]), f2bf(sm.tl[i4 + 3][hw]));
      *(ushort4*)&xtb[(hw0 + hw) * 512 + i0 + i4] = v;
    }
  }
}

// ---------------- K2: 72 x GEMM (M=512,N=1024,K=512), C = Wm @ X ------------------------
// 256x256 tile, BK=64, 8 waves (2M x 4N), per-wave 128x64 C. 8-phase-style schedule:
//   LDS 128 KiB = 2 dbuf x { A 2 halves x [128 rows][64 k] , B same }, rows 128 B.
//   Swizzle: LDS slot(16B) = linear; SOURCE slot = slot ^ (row&7); ds_read applies same
//   XOR -> stride-128B column reads hit 8 distinct 16B slots (b128-optimal depth 8).
//   Staging runs 2 K-tiles ahead into the CURRENT buffer:
//     P1: read A-lo(8) + B ni01(4) | MFMA 16      (A rows 0-63 of wave-half, all B t)
//     P2: read B ni23(4)           | MFMA 16      (B last read here)
//     P3: read A-hi(8), STAGE B0,B1(t+2) | MFMA 16  (A last read here)
//     P4: STAGE A0,A1(t+2) | MFMA 16, s_waitcnt vmcnt(8)  <- counted, never 0 mid-loop
//   Raw s_barrier (no compiler vmcnt(0) drain); s_setprio(1) around each MFMA cluster.
//   Gate proof: tile t+2's 8 loads issue P3/P4 of t; vmcnt(8) at (t+1).P4 retires them
//   before t+2.P1 reads; B stages follow P2's trailing barrier (B last read P2), A
//   stages follow P3's (A last read P3), so no overwrite of live data.
__global__ __launch_bounds__(512, 2) void k_gemm(const ushort* __restrict__ A,
                                                 const ushort* __restrict__ Bt,
                                                 ushort* __restrict__ C) {
  __shared__ __attribute__((aligned(128))) char smem[131072];
  const int id = blockIdx.x;
  const int batch = id & 7;        // XCD affinity: XT slab (1 MB) stays L2-resident
  const int rem = id >> 3;         // 0..71 per XCD lane: tap-major, 8 tiles per tap
  const int tap = rem >> 3;
  const int t8 = rem & 7;
  const int mt = t8 >> 2, nt = t8 & 3;
  const int m0 = mt * 256, n0 = nt * 256;
  const ushort* Ag = A + (size_t)(batch * 9 + tap) * (512 * 512);
  const ushort* Bg = Bt + (size_t)batch * (1024 * 512);
  ushort* Cg = C + (size_t)(batch * 9 + tap) * (512 * 1024);

  const int tid = threadIdx.x;
  const int w = tid >> 6, lane = tid & 63;
  const int wm = w >> 2, wn = w & 3;            // wave tile: rows wm*128, cols wn*64
  const int lq = lane >> 4, l15 = lane & 15, l7 = lane & 7;
  const int rlow = lane >> 3;                   // staging row low bits (0..7)
  const int ssw = (lane & 7) ^ rlow;            // inverse-swizzled source slot

  const char* pA = (const char*)Ag + (size_t)(m0 + w * 8 + rlow) * 1024 + ssw * 16;
  const char* pB = (const char*)Bg + (size_t)(n0 + w * 8 + rlow) * 1024 + ssw * 16;
  char* sAd = smem + w * 1024;            // + buf*65536 + h*16384 + rr*8192 (+lane*16 by HW)
  char* sBd = smem + 32768 + w * 1024;

#define GLL(srcp, dstp)                                                                     \
  __builtin_amdgcn_global_load_lds((const __attribute__((address_space(1))) void*)(srcp),   \
                                   (__attribute__((address_space(3))) void*)(dstp), 16, 0, 0)
#define STAGE_A(buf, h, kt)                                                                 \
  do {                                                                                      \
    GLL(pA + (h) * 131072 + (kt) * 128,         sAd + (buf) * 65536 + (h) * 16384);         \
    GLL(pA + (h) * 131072 + 65536 + (kt) * 128, sAd + (buf) * 65536 + (h) * 16384 + 8192);  \
  } while (0)
#define STAGE_B(buf, h, kt)                                                                 \
  do {                                                                                      \
    GLL(pB + (h) * 131072 + (kt) * 128,         sBd + (buf) * 65536 + (h) * 16384);         \
    GLL(pB + (h) * 131072 + 65536 + (kt) * 128, sBd + (buf) * 65536 + (h) * 16384 + 8192);  \
  } while (0)
#define CF asm volatile("" ::: "memory")
#define BAR()                          \
  do {                                 \
    CF;                                \
    __builtin_amdgcn_s_barrier();      \
    CF;                                \
  } while (0)

  // ds_read bases: row = (frag row base) + (lane&15); swizzle XOR = lane&7 (row&7 == l&7)
  const char* Ard = smem + wm * 16384 + l15 * 128;
  const char* Brd = smem + 32768 + (wn >> 1) * 16384 + (wn & 1) * 8192 + l15 * 128;
  const int s0o = (lq ^ l7) * 16;        // kk=0 slot (swizzled), bytes
  const int s1o = ((4 + lq) ^ l7) * 16;  // kk=1 slot

  f32x4 acc[8][4];
  const f32x4 z4 = {0.f, 0.f, 0.f, 0.f};
#pragma unroll
  for (int i = 0; i < 8; ++i)
#pragma unroll
    for (int n = 0; n < 4; ++n) acc[i][n] = z4;

  // Prologue: stage tiles 0 (buf0) and 1 (buf1); keep tile1's 8 loads in flight.
  STAGE_A(0, 0, 0); STAGE_A(0, 1, 0); STAGE_B(0, 0, 0); STAGE_B(0, 1, 0);
  STAGE_A(1, 0, 1); STAGE_A(1, 1, 1); STAGE_B(1, 0, 1); STAGE_B(1, 1, 1);
  asm volatile("s_waitcnt vmcnt(8)" ::: "memory");
  BAR();

#pragma unroll
  for (int t = 0; t < 8; ++t) {
    const int buf = t & 1;
    const char* Ab = Ard + buf * 65536;
    const char* Bb = Brd + buf * 65536;
    bf16x8 a[4][2], b[4][2];
    // ---- P1: A-lo + B ni01 reads; MFMA (mi 0-3 x ni 0-1) ----
#pragma unroll
    for (int i = 0; i < 4; ++i) {
      a[i][0] = *(const bf16x8*)(Ab + i * 2048 + s0o);
      a[i][1] = *(const bf16x8*)(Ab + i * 2048 + s1o);
    }
#pragma unroll
    for (int n = 0; n < 2; ++n) {
      b[n][0] = *(const bf16x8*)(Bb + n * 2048 + s0o);
      b[n][1] = *(const bf16x8*)(Bb + n * 2048 + s1o);
    }
    BAR();
    __builtin_amdgcn_s_setprio(1);
#pragma unroll
    for (int n = 0; n < 2; ++n)
#pragma unroll
      for (int i = 0; i < 4; ++i) {
        acc[i][n] = __builtin_amdgcn_mfma_f32_16x16x32_bf16(a[i][0], b[n][0], acc[i][n], 0, 0, 0);
        acc[i][n] = __builtin_amdgcn_mfma_f32_16x16x32_bf16(a[i][1], b[n][1], acc[i][n], 0, 0, 0);
      }
    __builtin_amdgcn_s_setprio(0);
    BAR();
    // ---- P2: B ni23 reads; MFMA (mi 0-3 x ni 2-3) ----
#pragma unroll
    for (int n = 2; n < 4; ++n) {
      b[n][0] = *(const bf16x8*)(Bb + n * 2048 + s0o);
      b[n][1] = *(const bf16x8*)(Bb + n * 2048 + s1o);
    }
    BAR();
    __builtin_amdgcn_s_setprio(1);
#pragma unroll
    for (int n = 2; n < 4; ++n)
#pragma unroll
      for (int i = 0; i < 4; ++i) {
        acc[i][n] = __builtin_amdgcn_mfma_f32_16x16x32_bf16(a[i][0], b[n][0], acc[i][n], 0, 0, 0);
        acc[i][n] = __builtin_amdgcn_mfma_f32_16x16x32_bf16(a[i][1], b[n][1], acc[i][n], 0, 0, 0);
      }
    __builtin_amdgcn_s_setprio(0);
    BAR();
    // ---- P3: A-hi reads + stage B halves of t+2; MFMA (mi 4-7 x ni 0-1) ----
    bf16x8 a2[4][2];
#pragma unroll
    for (int i = 0; i < 4; ++i) {
      a2[i][0] = *(const bf16x8*)(Ab + (4 + i) * 2048 + s0o);
      a2[i][1] = *(const bf16x8*)(Ab + (4 + i) * 2048 + s1o);
    }
    if (t < 6) { STAGE_B(buf, 0, t + 2); STAGE_B(buf, 1, t + 2); }
    BAR();
    __builtin_amdgcn_s_setprio(1);
#pragma unroll
    for (int n = 0; n < 2; ++n)
#pragma unroll
      for (int i = 0; i < 4; ++i) {
        acc[4 + i][n] = __builtin_amdgcn_mfma_f32_16x16x32_bf16(a2[i][0], b[n][0], acc[4 + i][n], 0, 0, 0);
        acc[4 + i][n] = __builtin_amdgcn_mfma_f32_16x16x32_bf16(a2[i][1], b[n][1], acc[4 + i][n], 0, 0, 0);
      }
    __builtin_amdgcn_s_setprio(0);
    BAR();
    // ---- P4: stage A halves of t+2; MFMA (mi 4-7 x ni 2-3); counted vmcnt gate ----
    if (t < 6) { STAGE_A(buf, 0, t + 2); STAGE_A(buf, 1, t + 2); }
    BAR();
    __builtin_amdgcn_s_setprio(1);
#pragma unroll
    for (int n = 2; n < 4; ++n)
#pragma unroll
      for (int i = 0; i < 4; ++i) {
        acc[4 + i][n] = __builtin_amdgcn_mfma_f32_16x16x32_bf16(a2[i][0], b[n][0], acc[4 + i][n], 0, 0, 0);
        acc[4 + i][n] = __builtin_amdgcn_mfma_f32_16x16x32_bf16(a2[i][1], b[n][1], acc[4 + i][n], 0, 0, 0);
      }
    __builtin_amdgcn_s_setprio(0);
    if (t < 6) {
      asm volatile("s_waitcnt vmcnt(8)" ::: "memory");  // next tile landed; 8 stay in flight
    } else if (t == 6) {
      asm volatile("s_waitcnt vmcnt(0)" ::: "memory");  // epilogue drain: tile 7 landed
    }
    BAR();
  }

  // Epilogue: stage C in LDS (128 rows x 264-ushort stride) in two wm passes, 16B stores.
  ushort* cs = (ushort*)smem;
#pragma unroll
  for (int p = 0; p < 2; ++p) {
    if (p) BAR();
    if (wm == p) {
#pragma unroll
      for (int mi2 = 0; mi2 < 8; ++mi2)
#pragma unroll
        for (int n = 0; n < 4; ++n) {
          const int row = mi2 * 16 + lq * 4;
          const int col = wn * 64 + n * 16 + l15;
          const f32x4 v = acc[mi2][n];
#pragma unroll
          for (int r = 0; r < 4; ++r) cs[(row + r) * 264 + col] = f2bf(v[r]);
        }
    }
    BAR();
#pragma unroll
    for (int j = 0; j < 8; ++j) {
      const int idx = j * 512 + tid;
      const int row = idx >> 5, c = idx & 31;
      *(uint4*)(Cg + (size_t)(m0 + p * 128 + row) * 1024 + n0 + c * 8) =
          *(const uint4*)(cs + row * 264 + c * 8);
    }
  }
#undef GLL
#undef STAGE_A
#undef STAGE_B
#undef CF
#undef BAR
}

// ---------------- K3: parity scatter + separable FIR, one (b,o) per block, 512 thr ------
// Stage1: V[kw][u][w] = sum_{kh,d} F*C[kh*3+kw][h][w], V row stride 36 (bank spread)
// Stage2: out[u][v] = (1/16) sum_{kw,d} F*V[kw][u][(v+t0+2d-1-kw)/2]
__global__ __launch_bounds__(512) void k_fir(const ushort* __restrict__ C,
                                             float* __restrict__ out) {
  const int bo = blockIdx.x;
  const int b = bo >> 9, o = bo & 511;
  __shared__ __attribute__((aligned(16))) ushort Ct[9 * 1024];
  __shared__ float V[3 * 64 * 36];
  const ushort* Cb = C + ((size_t)(b * 9) * 512 + o) * 1024;
  for (int c = threadIdx.x; c < 1152; c += 512) {
    const int tap = c >> 7, off = (c & 127) * 8;
    *(uint4*)&Ct[tap * 1024 + off] = *(const uint4*)&Cb[(size_t)tap * 524288 + off];
  }
  __syncthreads();
#pragma unroll
  for (int j = 0; j < 3; j++) {
    const int gidx = threadIdx.x + j * 512;  // (kw, u, w0/4)
    const int kw = gidx >> 9;
    const int rem = gidx & 511;
    const int u = rem >> 3;
    const int w0 = (rem & 7) * 4;
    float a0 = 0.f, a1 = 0.f, a2 = 0.f, a3 = 0.f;
#pragma unroll
    for (int kh = 0; kh < 3; kh++) {
      const int s0 = (kh + 1 + u) & 1;
#pragma unroll
      for (int d = 0; d < 2; d++) {
        const int h = (u + s0 + 2 * d - 1 - kh) >> 1;
        const bool ok = (h >= 0) & (h < 32);
        const float cf = ok ? ((s0 == d) ? 1.f : 3.f) : 0.f;
        const int hh = ok ? h : 0;
        const uint2 cv = *(const uint2*)&Ct[kh * 3072 + kw * 1024 + hh * 32 + w0];
        a0 += cf * bf2f((ushort)(cv.x & 0xffff));
        a1 += cf * bf2f((ushort)(cv.x >> 16));
        a2 += cf * bf2f((ushort)(cv.y & 0xffff));
        a3 += cf * bf2f((ushort)(cv.y >> 16));
      }
    }
    *(float4*)&V[kw * 2304 + u * 36 + w0] = make_float4(a0, a1, a2, a3);
  }
  __syncthreads();
  const size_t ob = (size_t)bo * 4096;
#pragma unroll
  for (int j = 0; j < 2; j++) {
    const int px4 = threadIdx.x + j * 512;
    const int u = px4 >> 4;
    const int v0 = (px4 & 15) * 4;
    float r[4] = {0.f, 0.f, 0.f, 0.f};
#pragma unroll
    for (int q = 0; q < 4; q++) {
      const int v = v0 + q;
#pragma unroll
      for (int kw = 0; kw < 3; kw++) {
        const int t0 = (kw + 1 + v) & 1;
#pragma unroll
        for (int d = 0; d < 2; d++) {
          const int wx = (v + t0 + 2 * d - 1 - kw) >> 1;
          const bool ok = (wx >= 0) & (wx < 32);
          const float cf = ok ? ((t0 == d) ? 1.f : 3.f) : 0.f;
          const int ww = ok ? wx : 0;
          r[q] += cf * V[kw * 2304 + u * 36 + ww];
        }
      }
      r[q] *= 0.0625f;
    }
    *(float4*)&out[ob + u * 64 + v0] = make_float4(r[0], r[1], r[2], r[3]);
  }
}

extern "C" void kernel_launch(void* const* d_in, const int* in_sizes, int n_in,
                              void* d_out, int out_size, void* d_ws, size_t ws_size,
                              hipStream_t stream) {
  (void)in_sizes; (void)n_in; (void)out_size; (void)ws_size;
  const float* x = (const float*)d_in[0];       // [8,512,32,32] fp32
  const float* styles = (const float*)d_in[1];  // [8,512] fp32
  const float* w = (const float*)d_in[2];       // [512,512,3,3] fp32
  float* out = (float*)d_out;                   // [8,512,64,64] fp32
  char* ws = (char*)d_ws;
  ushort* Wm = (ushort*)ws;                        // 37748736 B
  ushort* XT = (ushort*)(ws + 37748736);           // 8388608 B
  ushort* C = (ushort*)(ws + 37748736 + 8388608);  // 75497472 B

  k_prep<<<1024, 256, 0, stream>>>(w, styles, x, Wm, XT);
  k_gemm<<<576, 512, 0, stream>>>(Wm, XT, C);
  k_fir<<<4096, 512, 0, stream>>>(C, out);
}

// Round 2
// 157.008 us; speedup vs baseline: 1.0548x; 1.0548x over previous
//
#include <hip/hip_runtime.h>
#include <stdint.h>

// ModulatedConv (StyleGAN2 up-conv): B=8, Cin=Cout=512, K=3, 32x32 -> 64x64, fp32 I/O.
// Pipeline (3 kernels):
//   K1 k_prep:  blocks 0..511  = dcoef + Wm[b][tap][o][i] bf16 (37.75 MB), block per o
//               blocks 512..1023 = XT[b][hw][i] bf16 (8.39 MB) transpose
//   K2 k_gemm:  tap FUSED into M: per batch GEMM M=4608,N=1024,K=512. 192x256 tiles ->
//               768 blocks = exactly 3/CU (balanced rounds). 4-phase K-tile schedule,
//               T2 swizzle (0 conflicts), counted vmcnt(7), raw barriers, setprio,
//               kk-outer MFMA (independent chains).
//   K3 k_fir:   parity scatter + separable 4x4 FIR per (b,o), 512 thr, padded V

#define DI __device__ __forceinline__

typedef __bf16 bf16x8 __attribute__((ext_vector_type(8)));
typedef float f32x4 __attribute__((ext_vector_type(4)));

DI float bf2f(ushort u) { union { uint32_t i; float f; } v; v.i = ((uint32_t)u) << 16; return v.f; }
DI ushort f2bf(float f) {
  union { float f; uint32_t i; } v; v.f = f;
  uint32_t x = v.i;
  return (ushort)((x + 0x7FFFu + ((x >> 16) & 1u)) >> 16);  // RNE
}

#define GAIN (1.0f / 1536.0f)  // 1/sqrt(512*512*9)

// ---------------- K1: fused weight-prep (blocks 0..511) + x-transpose (512..1023) -------
__global__ __launch_bounds__(256) void k_prep(const float* __restrict__ w,
                                              const float* __restrict__ styles,
                                              const float* __restrict__ x,
                                              ushort* __restrict__ Wm,
                                              ushort* __restrict__ xt) {
  __shared__ union {
    struct { float ss[4096]; float dc[8]; float wred[4][8]; } wp;
    float tl[32][257];
  } sm;
  const int t = threadIdx.x;
  if (blockIdx.x < 512) {
    // ---- weight prep: block per o. Thread t owns i = 2t, 2t+1. ----
    const int o = blockIdx.x;
#pragma unroll
    for (int j = 0; j < 4; j++) {
      const int idx = (t + j * 256) * 4;
      *(float4*)&sm.wp.ss[idx] = *(const float4*)&styles[idx];
    }
    float wreg[18];
    const float* wp_ = w + o * 4608 + t * 18;
#pragma unroll
    for (int k = 0; k < 9; k++) {
      float2 v2 = *(const float2*)(wp_ + 2 * k);
      wreg[2 * k] = v2.x;
      wreg[2 * k + 1] = v2.y;
    }
    float q0 = 0.f, q1 = 0.f;
#pragma unroll
    for (int k = 0; k < 9; k++) {
      q0 += wreg[k] * wreg[k];
      q1 += wreg[9 + k] * wreg[9 + k];
    }
    __syncthreads();  // ss ready
    float pb[8];
#pragma unroll
    for (int b = 0; b < 8; b++) {
      float s0 = sm.wp.ss[b * 512 + 2 * t] + 1.0f;
      float s1 = sm.wp.ss[b * 512 + 2 * t + 1] + 1.0f;
      pb[b] = s0 * s0 * q0 + s1 * s1 * q1;
    }
#pragma unroll
    for (int b = 0; b < 8; b++)
#pragma unroll
      for (int off = 32; off > 0; off >>= 1) pb[b] += __shfl_down(pb[b], off, 64);
    const int wid = t >> 6, lane = t & 63;
    if (lane == 0) {
#pragma unroll
      for (int b = 0; b < 8; b++) sm.wp.wred[wid][b] = pb[b];
    }
    __syncthreads();
    if (t < 8)
      sm.wp.dc[t] = rsqrtf((sm.wp.wred[0][t] + sm.wp.wred[1][t] + sm.wp.wred[2][t] + sm.wp.wred[3][t]) *
                               (GAIN * GAIN) + 1e-8f);
    __syncthreads();
#pragma unroll
    for (int b = 0; b < 8; b++) {
      const float d = sm.wp.dc[b];
      const float s0 = GAIN * (sm.wp.ss[b * 512 + 2 * t] + 1.0f) * d;
      const float s1 = GAIN * (sm.wp.ss[b * 512 + 2 * t + 1] + 1.0f) * d;
      ushort* base = Wm + ((size_t)(b * 9) * 512 + o) * 512 + 2 * t;
#pragma unroll
      for (int tap = 0; tap < 9; tap++) {
        ushort2 val = make_ushort2(f2bf(wreg[tap] * s0), f2bf(wreg[9 + tap] * s1));
        *(ushort2*)(base + (size_t)tap * 262144) = val;
      }
    }
  } else {
    // ---- x transpose: tile 32 i x 256 hw ----
    const int idx = blockIdx.x - 512;
    const int hw0 = (idx & 3) * 256, i0 = ((idx >> 2) & 15) * 32, b = idx >> 6;
    const float* xb = x + b * (512 * 1024);
#pragma unroll
    for (int p = 0; p < 8; p++) {
      const int r = p * 4 + (t >> 6);
      const int c4 = (t & 63) * 4;
      float4 v = *(const float4*)&xb[(i0 + r) * 1024 + hw0 + c4];
      sm.tl[r][c4] = v.x; sm.tl[r][c4 + 1] = v.y; sm.tl[r][c4 + 2] = v.z; sm.tl[r][c4 + 3] = v.w;
    }
    __syncthreads();
    ushort* xtb = xt + b * (1024 * 512);
#pragma unroll
    for (int p = 0; p < 8; p++) {
      const int hw = p * 32 + (t >> 3);
      const int i4 = (t & 7) * 4;
      ushort4 v = make_ushort4(f2bf(sm.tl[i4][hw]), f2bf(sm.tl[i4 + 1][hw]),
                               f2bf(sm.tl[i4 + 2][hw]), f2bf(sm.tl[i4 + 3][hw]));
      *(ushort4*)&xtb[(hw0 + hw) * 512 + i0 + i4] = v;
    }
  }
}

// ---------------- K2: 8 x GEMM (M=4608,N=1024,K=512), C[b] = Wm[b] @ XT[b]^T ------------
// 192x256 tile, BK=64, 8 waves (2M x 4N), per-wave 96x64 (acc[6][4]).
// LDS 112 KiB = 2dbuf x { A[192][64] 24KB , B[256][64] 32KB }, rows 128 B, slot^=(row&7)
// swizzle (linear gl_load_lds dest + inverse-swizzled global source + swizzled ds_read).
// Per K-tile, 4 phases (reads before barrier, MFMA after; kk-outer = indep chains):
//   P1: read A mi0-2 (6) + B ni0-1 (4) | BAR | MFMA mi0-2 x ni0-1 (12) | BAR
//   P2: read B ni2-3 (4)               | BAR | MFMA mi0-2 x ni2-3 (12) | BAR
//   P3: read A mi3-5 (6), STAGE_B(t+2) | BAR | MFMA mi3-5 x ni0-1 (12) | BAR
//   P4: STAGE_A(t+2)                         | MFMA mi3-5 x ni2-3 (12) | vmcnt(7) | BAR
// Stage legality: B last read P2 -> stage P3; A last read P3 -> stage P4 (>=2 barriers).
// vmcnt(7): 7 loads/wave/tile; gate retires tile t+1's 7 while t+2's stay in flight.
__global__ __launch_bounds__(512, 2) void k_gemm(const ushort* __restrict__ A,
                                                 const ushort* __restrict__ Bt,
                                                 ushort* __restrict__ C) {
  __shared__ __attribute__((aligned(128))) char smem[114688];
  const int id = blockIdx.x;
  const int batch = id & 7;        // XCD affinity: XT slab (1 MB) stays L2-resident
  const int rem = id >> 3;         // 0..95: mt-major
  const int mt = rem >> 2, nt = rem & 3;
  const int m0 = mt * 192, n0 = nt * 256;
  const ushort* Ag = A + (size_t)batch * (4608 * 512);
  const ushort* Bg = Bt + (size_t)batch * (1024 * 512);
  ushort* Cg = C + (size_t)batch * (4608 * 1024);

  const int tid = threadIdx.x;
  const int w = tid >> 6, lane = tid & 63;
  const int wm = w >> 2, wn = w & 3;            // wave tile: rows wm*96, cols wn*64
  const int lq = lane >> 4, l15 = lane & 15, l7 = lane & 7;
  const int rlow = lane >> 3;                   // staging row low bits (0..7)
  const int ssw = (lane & 7) ^ rlow;            // inverse-swizzled source slot

  const char* pA = (const char*)Ag + (size_t)(m0 + w * 24 + rlow) * 1024 + ssw * 16;
  const char* pB = (const char*)Bg + (size_t)(n0 + w * 32 + rlow) * 1024 + ssw * 16;
  char* dA = smem + w * 3072;                   // wave's 3 A chunks (+buf*24576)
  char* dB = smem + 49152 + w * 4096;           // wave's 4 B chunks (+buf*32768)

#define GLL(srcp, dstp)                                                                     \
  __builtin_amdgcn_global_load_lds((const __attribute__((address_space(1))) void*)(srcp),   \
                                   (__attribute__((address_space(3))) void*)(dstp), 16, 0, 0)
#define STAGE_A(buf, kt)                                            \
  do {                                                              \
    GLL(pA + 0 * 8192 + (kt) * 128, dA + (buf) * 24576 + 0 * 1024); \
    GLL(pA + 1 * 8192 + (kt) * 128, dA + (buf) * 24576 + 1 * 1024); \
    GLL(pA + 2 * 8192 + (kt) * 128, dA + (buf) * 24576 + 2 * 1024); \
  } while (0)
#define STAGE_B(buf, kt)                                            \
  do {                                                              \
    GLL(pB + 0 * 8192 + (kt) * 128, dB + (buf) * 32768 + 0 * 1024); \
    GLL(pB + 1 * 8192 + (kt) * 128, dB + (buf) * 32768 + 1 * 1024); \
    GLL(pB + 2 * 8192 + (kt) * 128, dB + (buf) * 32768 + 2 * 1024); \
    GLL(pB + 3 * 8192 + (kt) * 128, dB + (buf) * 32768 + 3 * 1024); \
  } while (0)
#define CF asm volatile("" ::: "memory")
#define BAR()                          \
  do {                                 \
    CF;                                \
    __builtin_amdgcn_s_barrier();      \
    CF;                                \
  } while (0)

  // ds_read bases: row = frag row base + l15; swizzled slot = (kk*4+lq) ^ (row&7)
  const char* Ard = smem + (wm * 96 + l15) * 128;
  const char* Brd = smem + 49152 + (wn * 64 + l15) * 128;
  const int s0o = (lq ^ l7) * 16;        // kk=0 slot (swizzled), bytes
  const int s1o = ((4 + lq) ^ l7) * 16;  // kk=1 slot

  f32x4 acc[6][4];
  const f32x4 z4 = {0.f, 0.f, 0.f, 0.f};
#pragma unroll
  for (int i = 0; i < 6; ++i)
#pragma unroll
    for (int n = 0; n < 4; ++n) acc[i][n] = z4;

  // Prologue: stage tiles 0 (buf0) and 1 (buf1); keep tile1's 7 loads in flight.
  STAGE_A(0, 0); STAGE_B(0, 0);
  STAGE_A(1, 1); STAGE_B(1, 1);
  asm volatile("s_waitcnt vmcnt(7)" ::: "memory");
  BAR();

#pragma unroll
  for (int t = 0; t < 8; ++t) {
    const int buf = t & 1;
    const char* Ab = Ard + buf * 24576;
    const char* Bb = Brd + buf * 32768;
    bf16x8 a[3][2], a2[3][2], b[4][2];
    // ---- P1: read A mi0-2 + B ni0-1; MFMA mi0-2 x ni0-1 ----
#pragma unroll
    for (int i = 0; i < 3; ++i) {
      a[i][0] = *(const bf16x8*)(Ab + i * 2048 + s0o);
      a[i][1] = *(const bf16x8*)(Ab + i * 2048 + s1o);
    }
#pragma unroll
    for (int n = 0; n < 2; ++n) {
      b[n][0] = *(const bf16x8*)(Bb + n * 2048 + s0o);
      b[n][1] = *(const bf16x8*)(Bb + n * 2048 + s1o);
    }
    BAR();
    __builtin_amdgcn_s_setprio(1);
#pragma unroll
    for (int kk = 0; kk < 2; ++kk)
#pragma unroll
      for (int n = 0; n < 2; ++n)
#pragma unroll
        for (int i = 0; i < 3; ++i)
          acc[i][n] = __builtin_amdgcn_mfma_f32_16x16x32_bf16(a[i][kk], b[n][kk], acc[i][n], 0, 0, 0);
    __builtin_amdgcn_s_setprio(0);
    BAR();
    // ---- P2: read B ni2-3; MFMA mi0-2 x ni2-3 ----
#pragma unroll
    for (int n = 2; n < 4; ++n) {
      b[n][0] = *(const bf16x8*)(Bb + n * 2048 + s0o);
      b[n][1] = *(const bf16x8*)(Bb + n * 2048 + s1o);
    }
    BAR();
    __builtin_amdgcn_s_setprio(1);
#pragma unroll
    for (int kk = 0; kk < 2; ++kk)
#pragma unroll
      for (int n = 2; n < 4; ++n)
#pragma unroll
        for (int i = 0; i < 3; ++i)
          acc[i][n] = __builtin_amdgcn_mfma_f32_16x16x32_bf16(a[i][kk], b[n][kk], acc[i][n], 0, 0, 0);
    __builtin_amdgcn_s_setprio(0);
    BAR();
    // ---- P3: read A mi3-5 + stage B(t+2); MFMA mi3-5 x ni0-1 ----
#pragma unroll
    for (int i = 0; i < 3; ++i) {
      a2[i][0] = *(const bf16x8*)(Ab + (3 + i) * 2048 + s0o);
      a2[i][1] = *(const bf16x8*)(Ab + (3 + i) * 2048 + s1o);
    }
    if (t < 6) STAGE_B(buf, t + 2);
    BAR();
    __builtin_amdgcn_s_setprio(1);
#pragma unroll
    for (int kk = 0; kk < 2; ++kk)
#pragma unroll
      for (int n = 0; n < 2; ++n)
#pragma unroll
        for (int i = 0; i < 3; ++i)
          acc[3 + i][n] = __builtin_amdgcn_mfma_f32_16x16x32_bf16(a2[i][kk], b[n][kk], acc[3 + i][n], 0, 0, 0);
    __builtin_amdgcn_s_setprio(0);
    BAR();
    // ---- P4: stage A(t+2); MFMA mi3-5 x ni2-3 (all operands in regs); vmcnt gate ----
    if (t < 6) STAGE_A(buf, t + 2);
    __builtin_amdgcn_s_setprio(1);
#pragma unroll
    for (int kk = 0; kk < 2; ++kk)
#pragma unroll
      for (int n = 2; n < 4; ++n)
#pragma unroll
        for (int i = 0; i < 3; ++i)
          acc[3 + i][n] = __builtin_amdgcn_mfma_f32_16x16x32_bf16(a2[i][kk], b[n][kk], acc[3 + i][n], 0, 0, 0);
    __builtin_amdgcn_s_setprio(0);
    if (t < 6) {
      asm volatile("s_waitcnt vmcnt(7)" ::: "memory");  // t+1 landed; t+2's 7 in flight
    } else if (t == 6) {
      asm volatile("s_waitcnt vmcnt(0)" ::: "memory");  // epilogue drain: tile 7 landed
    }
    BAR();
  }

  // Epilogue: stage C in LDS (96 rows x 264-ushort stride) in two wm passes, 16B stores.
  ushort* cs = (ushort*)smem;
#pragma unroll
  for (int p = 0; p < 2; ++p) {
    if (p) BAR();
    if (wm == p) {
#pragma unroll
      for (int mi = 0; mi < 6; ++mi)
#pragma unroll
        for (int n = 0; n < 4; ++n) {
          const int row = mi * 16 + lq * 4;
          const int col = wn * 64 + n * 16 + l15;
          const f32x4 v = acc[mi][n];
#pragma unroll
          for (int r = 0; r < 4; ++r) cs[(row + r) * 264 + col] = f2bf(v[r]);
        }
    }
    BAR();
#pragma unroll
    for (int j = 0; j < 6; ++j) {
      const int idx = j * 512 + tid;
      const int row = idx >> 5, c = idx & 31;
      *(uint4*)(Cg + (size_t)(m0 + p * 96 + row) * 1024 + n0 + c * 8) =
          *(const uint4*)(cs + row * 264 + c * 8);
    }
  }
#undef GLL
#undef STAGE_A
#undef STAGE_B
#undef CF
#undef BAR
}

// ---------------- K3: parity scatter + separable FIR, one (b,o) per block, 512 thr ------
// Stage1: V[kw][u][w] = sum_{kh,d} F*C[kh*3+kw][h][w], V row stride 36 (bank spread)
// Stage2: out[u][v] = (1/16) sum_{kw,d} F*V[kw][u][(v+t0+2d-1-kw)/2]
__global__ __launch_bounds__(512) void k_fir(const ushort* __restrict__ C,
                                             float* __restrict__ out) {
  const int bo = blockIdx.x;
  const int b = bo >> 9, o = bo & 511;
  __shared__ __attribute__((aligned(16))) ushort Ct[9 * 1024];
  __shared__ float V[3 * 64 * 36];
  const ushort* Cb = C + ((size_t)(b * 9) * 512 + o) * 1024;
  for (int c = threadIdx.x; c < 1152; c += 512) {
    const int tap = c >> 7, off = (c & 127) * 8;
    *(uint4*)&Ct[tap * 1024 + off] = *(const uint4*)&Cb[(size_t)tap * 524288 + off];
  }
  __syncthreads();
#pragma unroll
  for (int j = 0; j < 3; j++) {
    const int gidx = threadIdx.x + j * 512;  // (kw, u, w0/4)
    const int kw = gidx >> 9;
    const int rem = gidx & 511;
    const int u = rem >> 3;
    const int w0 = (rem & 7) * 4;
    float a0 = 0.f, a1 = 0.f, a2 = 0.f, a3 = 0.f;
#pragma unroll
    for (int kh = 0; kh < 3; kh++) {
      const int s0 = (kh + 1 + u) & 1;
#pragma unroll
      for (int d = 0; d < 2; d++) {
        const int h = (u + s0 + 2 * d - 1 - kh) >> 1;
        const bool ok = (h >= 0) & (h < 32);
        const float cf = ok ? ((s0 == d) ? 1.f : 3.f) : 0.f;
        const int hh = ok ? h : 0;
        const uint2 cv = *(const uint2*)&Ct[kh * 3072 + kw * 1024 + hh * 32 + w0];
        a0 += cf * bf2f((ushort)(cv.x & 0xffff));
        a1 += cf * bf2f((ushort)(cv.x >> 16));
        a2 += cf * bf2f((ushort)(cv.y & 0xffff));
        a3 += cf * bf2f((ushort)(cv.y >> 16));
      }
    }
    *(float4*)&V[kw * 2304 + u * 36 + w0] = make_float4(a0, a1, a2, a3);
  }
  __syncthreads();
  const size_t ob = (size_t)bo * 4096;
#pragma unroll
  for (int j = 0; j < 2; j++) {
    const int px4 = threadIdx.x + j * 512;
    const int u = px4 >> 4;
    const int v0 = (px4 & 15) * 4;
    float r[4] = {0.f, 0.f, 0.f, 0.f};
#pragma unroll
    for (int q = 0; q < 4; q++) {
      const int v = v0 + q;
#pragma unroll
      for (int kw = 0; kw < 3; kw++) {
        const int t0 = (kw + 1 + v) & 1;
#pragma unroll
        for (int d = 0; d < 2; d++) {
          const int wx = (v + t0 + 2 * d - 1 - kw) >> 1;
          const bool ok = (wx >= 0) & (wx < 32);
          const float cf = ok ? ((t0 == d) ? 1.f : 3.f) : 0.f;
          const int ww = ok ? wx : 0;
          r[q] += cf * V[kw * 2304 + u * 36 + ww];
        }
      }
      r[q] *= 0.0625f;
    }
    *(float4*)&out[ob + u * 64 + v0] = make_float4(r[0], r[1], r[2], r[3]);
  }
}

extern "C" void kernel_launch(void* const* d_in, const int* in_sizes, int n_in,
                              void* d_out, int out_size, void* d_ws, size_t ws_size,
                              hipStream_t stream) {
  (void)in_sizes; (void)n_in; (void)out_size; (void)ws_size;
  const float* x = (const float*)d_in[0];       // [8,512,32,32] fp32
  const float* styles = (const float*)d_in[1];  // [8,512] fp32
  const float* w = (const float*)d_in[2];       // [512,512,3,3] fp32
  float* out = (float*)d_out;                   // [8,512,64,64] fp32
  char* ws = (char*)d_ws;
  ushort* Wm = (ushort*)ws;                        // 37748736 B
  ushort* XT = (ushort*)(ws + 37748736);           // 8388608 B
  ushort* C = (ushort*)(ws + 37748736 + 8388608);  // 75497472 B

  k_prep<<<1024, 256, 0, stream>>>(w, styles, x, Wm, XT);
  k_gemm<<<768, 512, 0, stream>>>(Wm, XT, C);
  k_fir<<<4096, 512, 0, stream>>>(C, out);
}